// Round 15
// baseline (433.989 us; speedup 1.0000x reference)
//
#include <hip/hip_runtime.h>
#include <hip/hip_fp16.h>
#include <hip/hip_cooperative_groups.h>

namespace cg = cooperative_groups;

#define NG 16     // num_graphs (fixed by problem)
#define D 64      // feature width at every aggregation point
#define SLOT 32   // CSR slots/node; max in-degree ~Poisson(8.5), P(>=32)~1e-11
#define INP 68    // padded LDS row stride (D+4): float4-aligned, conflict-free
#define NPB 64    // nodes per tile (512 threads, 8 lanes/node)

// fp16 feature rows: 64 halfs = 128 B = 8 float4s. Tables have N+1 rows;
// row N is all-zero (gather pad target).
union HF4 { float4 f4; __half2 h2[4]; };
union HF2 { float2 f2; __half2 h2[2]; };

struct Params {
  const float* x; const int* ei; const int* batch;
  const float* W1a; const float* b1a; const float* W1b; const float* b1b;
  const float* g1; const float* be1;
  const float* W2a; const float* b2a; const float* W2b; const float* b2b;
  const float* g2; const float* be2;
  float* h1h; float* xh; int* col;
  float* sum1; float* sq1; float* pool; float* cnt; float* sq2; int* fill;
  int* zero_base; int zero_n;
  float* out;
  int N, E, per, tmul, n4, ntiles;
  float invN;
};

// Tree-reduce rows 0..31 (+32..63 as a second half) of s_in down to row 0 /
// row 32. 64 float columns per half, float4 per lane.
__device__ __forceinline__ void tree_reduce_2x32(float* s_in, int tid) {
#pragma unroll
  for (int s = 16; s >= 1; s >>= 1) {
    if (tid < 32 * s) {
      int h = tid / (16 * s);
      int r = (tid / 16) % s;
      int qq = tid & 15;
      float4* a = (float4*)&s_in[(h * 32 + r) * INP + qq * 4];
      const float4 b = *(const float4*)&s_in[(h * 32 + r + s) * INP + qq * 4];
      a->x += b.x; a->y += b.y; a->z += b.z; a->w += b.w;
    }
    __syncthreads();
  }
}

// Stage Wa+Wb into LDS as fp16 (coalesced float4 reads).
template <int MID>
__device__ __forceinline__ void stage_weights(__half* s_Wa, __half* s_Wb,
                                              const float* Wa, const float* Wb,
                                              int tid) {
  const float4* wa4 = (const float4*)Wa;
  const float4* wb4 = (const float4*)Wb;
  __half2* sa2 = (__half2*)s_Wa;
  __half2* sb2 = (__half2*)s_Wb;
  constexpr int NW = D * MID / 4;
#pragma unroll
  for (int i = tid; i < NW; i += 512) {
    float4 a = wa4[i];
    float4 b = wb4[i];
    sa2[2 * i + 0] = __floats2half2_rn(a.x, a.y);
    sa2[2 * i + 1] = __floats2half2_rn(a.z, a.w);
    sb2[2 * i + 0] = __floats2half2_rn(b.x, b.y);
    sb2[2 * i + 1] = __floats2half2_rn(b.z, b.w);
  }
}

// ---------------------------------------------------------------------------
// One 64-node tile: fp16 gather (8 lanes/node, uniform 8-wide pad-redirect
// rounds — R13's measured-best) + fp32 MLP (fp16 LDS weights, shfl mids) +
// epilogue (EPI==1: fp16 store + BN stats; EPI==2: pool+sumsq+cnt, no store).
// Caller must __syncthreads() between tiles (s_in/s_cnt reuse).
// ---------------------------------------------------------------------------
template <int MID, bool FOLD_BN, int EPI>
__device__ __forceinline__ void layer_tile(
    int base, int N, int tid,
    const float4* __restrict__ feat4, const int* __restrict__ col,
    const int* __restrict__ deg,
    const float* __restrict__ ba, const float* __restrict__ bb,
    float2* __restrict__ out2, const int* __restrict__ batch,
    float* __restrict__ st_sum, float* __restrict__ st_sq,
    float* __restrict__ cnt,
    float* s_in, const __half* s_Wa, const __half* s_Wb,
    const float* s_bna, const float* s_bnb, int* s_cnt) {
  if (EPI == 2 && tid < 2) s_cnt[tid] = 0;

  // ---- Phase A: 8 lanes/node fp16 gather, uniform 8-wide rounds ----
  {
    int slot = tid >> 3;          // 0..63
    int q8 = tid & 7;             // lane covers features 8*q8 .. 8*q8+7
    int node = base + slot;
    if (node < N) {
      int d = min(deg[node], SLOT);
      const int* cl = col + node * SLOT;
      float acc[8];
      {
        HF4 s; s.f4 = feat4[(size_t)node * 8 + q8];   // self term
#pragma unroll
        for (int i = 0; i < 4; i++) {
          float2 f = __half22float2(s.h2[i]);
          acc[2 * i] = f.x; acc[2 * i + 1] = f.y;
        }
      }
      int dpad = (d + 7) & ~7;    // rounds of exactly 8 unconditional loads
      for (int j = 0; j < dpad; j += 8) {
        int4 sa = *(const int4*)(cl + j);     // SLOT=32: in-bounds
        int4 sb = *(const int4*)(cl + j + 4);
        int i0 = (j + 0 < d) ? sa.x : N;      // pad -> zero row
        int i1 = (j + 1 < d) ? sa.y : N;
        int i2 = (j + 2 < d) ? sa.z : N;
        int i3 = (j + 3 < d) ? sa.w : N;
        int i4 = (j + 4 < d) ? sb.x : N;
        int i5 = (j + 5 < d) ? sb.y : N;
        int i6 = (j + 6 < d) ? sb.z : N;
        int i7 = (j + 7 < d) ? sb.w : N;
        HF4 u0, u1, u2, u3, u4, u5, u6, u7;
        u0.f4 = feat4[(size_t)i0 * 8 + q8];
        u1.f4 = feat4[(size_t)i1 * 8 + q8];
        u2.f4 = feat4[(size_t)i2 * 8 + q8];
        u3.f4 = feat4[(size_t)i3 * 8 + q8];
        u4.f4 = feat4[(size_t)i4 * 8 + q8];
        u5.f4 = feat4[(size_t)i5 * 8 + q8];
        u6.f4 = feat4[(size_t)i6 * 8 + q8];
        u7.f4 = feat4[(size_t)i7 * 8 + q8];
#pragma unroll
        for (int i = 0; i < 4; i++) {
          float2 f0 = __half22float2(u0.h2[i]), f1 = __half22float2(u1.h2[i]);
          float2 f2 = __half22float2(u2.h2[i]), f3 = __half22float2(u3.h2[i]);
          float2 f4 = __half22float2(u4.h2[i]), f5 = __half22float2(u5.h2[i]);
          float2 f6 = __half22float2(u6.h2[i]), f7 = __half22float2(u7.h2[i]);
          acc[2 * i]     += (f0.x + f1.x + f2.x + f3.x) + (f4.x + f5.x + f6.x + f7.x);
          acc[2 * i + 1] += (f0.y + f1.y + f2.y + f3.y) + (f4.y + f5.y + f6.y + f7.y);
        }
      }
      if (FOLD_BN) {
        float dp = (float)(d + 1);
        int c = q8 * 8;
#pragma unroll
        for (int i = 0; i < 8; i++)
          acc[i] = s_bna[c + i] * acc[i] + dp * s_bnb[c + i];
      }
      *(float4*)&s_in[slot * INP + q8 * 8] =
          make_float4(acc[0], acc[1], acc[2], acc[3]);
      *(float4*)&s_in[slot * INP + q8 * 8 + 4] =
          make_float4(acc[4], acc[5], acc[6], acc[7]);
    }
  }
  __syncthreads();

  // ---- Phase B: register-tiled MLP (fp32 math, fp16 LDS weights) ----
  int q = tid & 15;               // lane within 16-group (output cols 4q..4q+3)
  int r2 = tid >> 4;              // 0..31 -> nodes 2r2, 2r2+1
  int n0 = 2 * r2, n1 = n0 + 1;
  int node0 = base + n0, node1 = base + n1;
  constexpr int C1 = MID / 16;    // stage-1 cols per thread (2 or 4)
  float4 o0, o1;
  {
    float acc0[C1], acc1[C1];
#pragma unroll
    for (int u = 0; u < C1; u++) { acc0[u] = ba[q * C1 + u]; acc1[u] = acc0[u]; }
#pragma unroll 4
    for (int j = 0; j < D; j++) {
      float v0 = s_in[n0 * INP + j];
      float v1 = s_in[n1 * INP + j];
      if constexpr (C1 == 2) {
        float2 w = __half22float2(((const __half2*)s_Wa)[j * 16 + q]);
        acc0[0] += v0 * w.x; acc0[1] += v0 * w.y;
        acc1[0] += v1 * w.x; acc1[1] += v1 * w.y;
      } else {
        HF2 u; u.f2 = ((const float2*)s_Wa)[j * 16 + q];
        float2 wA = __half22float2(u.h2[0]);
        float2 wB = __half22float2(u.h2[1]);
        acc0[0] += v0 * wA.x; acc0[1] += v0 * wA.y;
        acc0[2] += v0 * wB.x; acc0[3] += v0 * wB.y;
        acc1[0] += v1 * wA.x; acc1[1] += v1 * wA.y;
        acc1[2] += v1 * wB.x; acc1[3] += v1 * wB.y;
      }
    }
#pragma unroll
    for (int u = 0; u < C1; u++) {
      acc0[u] = fmaxf(acc0[u], 0.f);
      acc1[u] = fmaxf(acc1[u], 0.f);
    }

    // stage 2: cols 4q..4q+3; mid[k] owner lane = k/C1, reg = k%C1
    o0 = *(const float4*)(bb + q * 4);
    o1 = o0;
#pragma unroll 8
    for (int k = 0; k < MID; k++) {
      float m0 = __shfl(acc0[k % C1], k / C1, 16);
      float m1 = __shfl(acc1[k % C1], k / C1, 16);
      HF2 u; u.f2 = ((const float2*)s_Wb)[k * 16 + q];
      float2 wA = __half22float2(u.h2[0]);
      float2 wB = __half22float2(u.h2[1]);
      o0.x += m0 * wA.x; o0.y += m0 * wA.y; o0.z += m0 * wB.x; o0.w += m0 * wB.y;
      o1.x += m1 * wA.x; o1.y += m1 * wA.y; o1.z += m1 * wB.x; o1.w += m1 * wB.y;
    }
    o0.x = fmaxf(o0.x, 0.f); o0.y = fmaxf(o0.y, 0.f);
    o0.z = fmaxf(o0.z, 0.f); o0.w = fmaxf(o0.w, 0.f);
    o1.x = fmaxf(o1.x, 0.f); o1.y = fmaxf(o1.y, 0.f);
    o1.z = fmaxf(o1.z, 0.f); o1.w = fmaxf(o1.w, 0.f);
    if (EPI == 1) {
      if (node0 < N) {
        HF2 u;
        u.h2[0] = __floats2half2_rn(o0.x, o0.y);
        u.h2[1] = __floats2half2_rn(o0.z, o0.w);
        out2[(size_t)node0 * 16 + q] = u.f2;
      }
      if (node1 < N) {
        HF2 u;
        u.h2[0] = __floats2half2_rn(o1.x, o1.y);
        u.h2[1] = __floats2half2_rn(o1.z, o1.w);
        out2[(size_t)node1 * 16 + q] = u.f2;
      }
    }
    if (node0 >= N) o0 = make_float4(0.f, 0.f, 0.f, 0.f);
    if (node1 >= N) o1 = make_float4(0.f, 0.f, 0.f, 0.f);
  }

  if (EPI == 1) {
    // ---- BN-stats epilogue: block tree-reduce sum + sumsq, 128 atomics ----
    __syncthreads();   // all s_in reads done; reuse s_in as reduce buffer
    *(float4*)&s_in[r2 * INP + q * 4] =
        make_float4(o0.x + o1.x, o0.y + o1.y, o0.z + o1.z, o0.w + o1.w);
    *(float4*)&s_in[(32 + r2) * INP + q * 4] =
        make_float4(o0.x * o0.x + o1.x * o1.x, o0.y * o0.y + o1.y * o1.y,
                    o0.z * o0.z + o1.z * o1.z, o0.w * o0.w + o1.w * o1.w);
    __syncthreads();
    tree_reduce_2x32(s_in, tid);
    if (tid < D) {
      atomicAdd(&st_sum[tid], s_in[tid]);
      atomicAdd(&st_sq[tid], s_in[32 * INP + tid]);
    }
  }

  if (EPI == 2) {
    // ---- Pool epilogue: <=2 graphs per 64-node tile (sorted batch) ----
    int b0 = (node0 < N) ? batch[node0] : -1;
    int b1 = (node1 < N) ? batch[node1] : -1;
    int g_lo = batch[base];
    int g_hi = batch[min(base + NPB - 1, N - 1)];

    __syncthreads();   // s_in reads done; s_cnt init visible
    // ONLY q==0: the 16 q-lanes of an r2-group share the same two nodes.
    if (q == 0) {
      atomicAdd(&s_cnt[0], (b0 == g_lo ? 1 : 0) + (b1 == g_lo ? 1 : 0));
      if (g_hi != g_lo)
        atomicAdd(&s_cnt[1], (b0 == g_hi ? 1 : 0) + (b1 == g_hi ? 1 : 0));
    }

    float w0 = (b0 == g_lo) ? 1.f : 0.f;
    float w1 = (b1 == g_lo) ? 1.f : 0.f;
    *(float4*)&s_in[r2 * INP + q * 4] =
        make_float4(w0 * o0.x + w1 * o1.x, w0 * o0.y + w1 * o1.y,
                    w0 * o0.z + w1 * o1.z, w0 * o0.w + w1 * o1.w);
    *(float4*)&s_in[(32 + r2) * INP + q * 4] =
        make_float4(o0.x * o0.x + o1.x * o1.x, o0.y * o0.y + o1.y * o1.y,
                    o0.z * o0.z + o1.z * o1.z, o0.w * o0.w + o1.w * o1.w);
    __syncthreads();
    tree_reduce_2x32(s_in, tid);
    if (tid < D) {
      atomicAdd(&st_sum[g_lo * D + tid], s_in[tid]);
      atomicAdd(&st_sq[tid], s_in[32 * INP + tid]);
    }
    if (tid == 0) atomicAdd(&cnt[g_lo], (float)s_cnt[0]);

    if (g_hi != g_lo) {   // block-uniform branch
      __syncthreads();
      float u0 = (b0 == g_hi) ? 1.f : 0.f;
      float u1 = (b1 == g_hi) ? 1.f : 0.f;
      *(float4*)&s_in[r2 * INP + q * 4] =
          make_float4(u0 * o0.x + u1 * o1.x, u0 * o0.y + u1 * o1.y,
                      u0 * o0.z + u1 * o1.z, u0 * o0.w + u1 * o1.w);
      *(float4*)&s_in[(32 + r2) * INP + q * 4] = make_float4(0.f, 0.f, 0.f, 0.f);
      __syncthreads();
      tree_reduce_2x32(s_in, tid);
      if (tid < D) atomicAdd(&st_sum[g_hi * D + tid], s_in[tid]);
      if (tid == 0) atomicAdd(&cnt[g_hi], (float)s_cnt[1]);
    }
  }
}

// ---------------------------------------------------------------------------
// Single cooperative kernel: zero-init -> convert -> CSR -> layer1 -> layer2
// -> final, with grid.sync() replacing dispatch boundaries (~17us each, R14
// ledger). Grid sized by occupancy so all blocks are co-resident.
// ---------------------------------------------------------------------------
__global__ __launch_bounds__(512, 2) void gin_coop_kernel(Params p) {
  __shared__ float s_in[NPB * INP];
  __shared__ __half s_Wa[D * D];
  __shared__ __half s_Wb[D * D];
  __shared__ float s_bna[D];
  __shared__ float s_bnb[D];
  __shared__ int s_cnt[2];

  cg::grid_group grid = cg::this_grid();
  int tid = threadIdx.x;
  int gthread = blockIdx.x * 512 + tid;
  int gstride = gridDim.x * 512;

  // ---- Phase 0: zero stats+fill; x -> fp16; zero pad rows ----
  for (int i = gthread; i < p.zero_n; i += gstride) p.zero_base[i] = 0;
  for (int t = gthread; t < p.n4; t += gstride) {
    float4 v = ((const float4*)p.x)[t];
    HF2 u;
    u.h2[0] = __floats2half2_rn(v.x, v.y);
    u.h2[1] = __floats2half2_rn(v.z, v.w);
    ((float2*)p.xh)[t] = u.f2;
  }
  if (gthread < 16) {
    float4 z = make_float4(0.f, 0.f, 0.f, 0.f);
    if (gthread < 8) ((float4*)(p.xh + (size_t)p.N * D / 2))[gthread] = z;
    else ((float4*)(p.h1h + (size_t)p.N * D / 2))[gthread - 8] = z;
  }
  grid.sync();

  // ---- Phase 1: CSR build (fill zeroed in phase 0) ----
  for (int e = gthread; e < p.E; e += gstride) {
    int src = p.ei[e];
    int dst = p.ei[p.E + e];
    int thr = (e / p.per) * p.tmul;     // compiler magic-div
    if (src >= thr && dst >= thr) {
      int k = atomicAdd(&p.fill[dst], 1);
      if (k < SLOT) p.col[dst * SLOT + k] = src;
    }
  }
  grid.sync();

  // ---- Phase 2: layer 1 (gather x + MLP1 -> h1h fp16 + BN1 stats) ----
  stage_weights<32>(s_Wa, s_Wb, p.W1a, p.W1b, tid);
  __syncthreads();
  for (int tile = blockIdx.x; tile < p.ntiles; tile += gridDim.x) {
    layer_tile<32, false, 1>(tile * NPB, p.N, tid,
        (const float4*)p.xh, p.col, p.fill, p.b1a, p.b1b,
        (float2*)p.h1h, nullptr, p.sum1, p.sq1, nullptr,
        s_in, s_Wa, s_Wb, s_bna, s_bnb, s_cnt);
    __syncthreads();   // s_in reuse across tiles
  }
  grid.sync();

  // ---- Phase 3: layer 2 (BN1 folded; pool + sumsq epilogue, no h2) ----
  stage_weights<64>(s_Wa, s_Wb, p.W2a, p.W2b, tid);
  if (tid < D) {
    float mean = p.sum1[tid] * p.invN;
    float var = p.sq1[tid] * p.invN - mean * mean;
    float av = p.g1[tid] * rsqrtf(var + 1e-5f);
    s_bna[tid] = av;
    s_bnb[tid] = p.be1[tid] - mean * av;
  }
  __syncthreads();
  for (int tile = blockIdx.x; tile < p.ntiles; tile += gridDim.x) {
    layer_tile<64, true, 2>(tile * NPB, p.N, tid,
        (const float4*)p.h1h, p.col, p.fill, p.b2a, p.b2b,
        nullptr, p.batch, p.pool, p.sq2, p.cnt,
        s_in, s_Wa, s_Wb, s_bna, s_bnb, s_cnt);
    __syncthreads();
  }
  grid.sync();

  // ---- Phase 4: final (BN2 coeffs + affine + mean) ----
  if (blockIdx.x == 0 && tid < D) {
    float s = 0.f;
#pragma unroll
    for (int g = 0; g < NG; g++) s += p.pool[g * D + tid];
    float mean = s * p.invN;
    float var = p.sq2[tid] * p.invN - mean * mean;
    float a = p.g2[tid] * rsqrtf(var + 1e-5f);
    float b = p.be2[tid] - mean * a;
#pragma unroll
    for (int g = 0; g < NG; g++) {
      float n = p.cnt[g];
      p.out[g * D + tid] = (a * p.pool[g * D + tid] + n * b) / fmaxf(n, 1.f);
    }
  }
}

extern "C" void kernel_launch(void* const* d_in, const int* in_sizes, int n_in,
                              void* d_out, int out_size, void* d_ws, size_t ws_size,
                              hipStream_t stream) {
  Params p;
  p.x   = (const float*)d_in[0];
  p.ei  = (const int*)d_in[1];
  p.batch = (const int*)d_in[2];
  p.W1a = (const float*)d_in[5];  p.b1a = (const float*)d_in[6];
  p.W1b = (const float*)d_in[7];  p.b1b = (const float*)d_in[8];
  p.g1  = (const float*)d_in[9];  p.be1 = (const float*)d_in[10];
  p.W2a = (const float*)d_in[11]; p.b2a = (const float*)d_in[12];
  p.W2b = (const float*)d_in[13]; p.b2b = (const float*)d_in[14];
  p.g2  = (const float*)d_in[15]; p.be2 = (const float*)d_in[16];

  p.N = in_sizes[0] / D;          // 100000
  p.E = in_sizes[1] / 2;          // 1600000
  p.per = p.E / NG;               // 100000
  p.tmul = p.N / NG;              // 6250
  p.n4 = p.N * D / 4;
  p.ntiles = (p.N + NPB - 1) / NPB;   // 1563
  p.invN = 1.f / (float)p.N;

  float* ws = (float*)d_ws;
  size_t ndh = (size_t)(p.N + 1) * D / 2;   // fp16 table floats (N+1 rows)
  p.h1h = ws;
  p.xh  = ws + ndh;
  p.col = (int*)(ws + 2 * ndh);
  float* stats = ws + 2 * ndh + (size_t)p.N * SLOT;
  p.sum1 = stats;
  p.sq1  = stats + 64;
  p.pool = stats + 128;
  p.cnt  = stats + 128 + NG * D;
  p.sq2  = stats + 144 + NG * D;
  p.fill = (int*)(stats + 208 + NG * D);
  p.zero_base = (int*)stats;
  p.zero_n = 208 + NG * D + p.N;      // stats block + fill, in 4B words
  p.out = (float*)d_out;

  // Grid = co-resident capacity (occupancy-derived; deterministic per build).
  int bpc = 0;
  hipOccupancyMaxActiveBlocksPerMultiprocessor(
      &bpc, reinterpret_cast<const void*>(gin_coop_kernel), 512, 0);
  if (bpc < 1) bpc = 1;
  int G = bpc * 256;                  // 256 CUs on MI355X
  if (G > p.ntiles) G = p.ntiles;

  void* args[] = { &p };
  hipLaunchCooperativeKernel(reinterpret_cast<void*>(gin_coop_kernel),
                             dim3(G), dim3(512), args, 0, stream);
}

// Round 16
// 422.237 us; speedup vs baseline: 1.0278x; 1.0278x over previous
//
#include <hip/hip_runtime.h>
#include <hip/hip_fp16.h>

#define NG 16     // num_graphs (fixed by problem)
#define D 64      // feature width at every aggregation point
#define SLOT 32   // CSR slots/node; max in-degree ~Poisson(8.5), P(>=32)~1e-11
#define INP 68    // padded LDS row stride (D+4): float4-aligned, conflict-free
#define NPB 64    // nodes per block (512 threads, 8 lanes/node)

// fp16 feature rows: 64 halfs = 128 B = 8 float4s. Tables have N+1 rows;
// row N is all-zero (gather pad target).
union HF4 { float4 f4; __half2 h2[4]; };
union HF2 { float2 f2; __half2 h2[2]; };

// ---------------------------------------------------------------------------
// Fused prep: x->fp16 convert (t < n4) + CSR build (t < E) + pad-row zeroing.
// n4 == E == 1.6M for this problem, so one grid covers both jobs. (R14's win.)
// fill[] must be zeroed beforehand (memset on same stream).
// ---------------------------------------------------------------------------
__global__ void prep_kernel(const float* __restrict__ x,
                            float2* __restrict__ xh, int n4,
                            float4* __restrict__ xz, float4* __restrict__ hz,
                            const int* __restrict__ ei,
                            int* __restrict__ fill, int* __restrict__ col,
                            int E, int per, int tmul) {
  int t = blockIdx.x * 256 + threadIdx.x;
  if (blockIdx.x == 0 && threadIdx.x < 16) {
    float4 z = make_float4(0.f, 0.f, 0.f, 0.f);
    if (threadIdx.x < 8) xz[threadIdx.x] = z;
    else hz[threadIdx.x - 8] = z;
  }
  if (t < n4) {
    float4 v = ((const float4*)x)[t];
    HF2 u;
    u.h2[0] = __floats2half2_rn(v.x, v.y);
    u.h2[1] = __floats2half2_rn(v.z, v.w);
    xh[t] = u.f2;
  }
  if (t < E) {
    int src = ei[t];
    int dst = ei[E + t];
    int thr = (t / per) * tmul;       // compiler magic-div
    if (src >= thr && dst >= thr) {
      int k = atomicAdd(&fill[dst], 1);
      if (k < SLOT) col[dst * SLOT + k] = src;
    }
  }
}

// Tree-reduce rows 0..31 (+32..63 as a second half) of s_in down to row 0 /
// row 32. 64 float columns per half, float4 per lane.
__device__ __forceinline__ void tree_reduce_2x32(float* s_in, int tid) {
#pragma unroll
  for (int s = 16; s >= 1; s >>= 1) {
    if (tid < 32 * s) {
      int h = tid / (16 * s);          // 0 = first half, 1 = second half
      int r = (tid / 16) % s;
      int qq = tid & 15;
      float4* a = (float4*)&s_in[(h * 32 + r) * INP + qq * 4];
      const float4 b = *(const float4*)&s_in[(h * 32 + r + s) * INP + qq * 4];
      a->x += b.x; a->y += b.y; a->z += b.z; a->w += b.w;
    }
    __syncthreads();
  }
}

// ---------------------------------------------------------------------------
// Fused layer (R13's measured-best shape): fp16 gather + (optional BN fold) +
// fp32 MLP + epilogue.
//  EPI==1 (layer 1): store h as fp16 to `out2`, block-reduce BN stats.
//  EPI==2 (layer 2): no per-node store; per-graph pool sums + sumsq + counts;
//    LAST block (ctr-based) computes the final BN2+mean output — no separate
//    final dispatch (R15 fold; ~17us/dispatch-boundary per R14 ledger).
// Block = 512 threads, 64 nodes (R12: 256-thr blocks regressed).
//  Phase A: 8 lanes/node, rounds of EXACTLY 8 unconditional float4 loads
//    (pad -> zero row N): avg-degree nodes finish gather in ONE latency trip.
//  Phase B: thread (q,r2) -> nodes {2r2,2r2+1}; stage-1 mids in registers,
//    stage-2 via 16-lane __shfl; Wa+Wb in LDS as fp16.
// __launch_bounds__ 2nd arg (empirical, 512-thr blocks): VGPR cap = 256/arg.
//   arg=8 -> 32 (R5 spill), arg=4 -> 64 (R6 spill), arg=2 -> 128 (safe).
// ---------------------------------------------------------------------------
template <int MID, bool FOLD_BN, int EPI>
__global__ __launch_bounds__(512, 2) void fused_layer_kernel(
    const float4* __restrict__ feat4,   // fp16 table, 8 float4/row, N+1 rows
    const int* __restrict__ col, const int* __restrict__ deg,
    const float* __restrict__ bn_sum, const float* __restrict__ bn_sq,
    const float* __restrict__ bn_gamma, const float* __restrict__ bn_beta,
    float invN,
    const float* __restrict__ Wa, const float* __restrict__ ba,
    const float* __restrict__ Wb, const float* __restrict__ bb,
    float2* __restrict__ out2,          // EPI==1 only (fp16 rows)
    const int* __restrict__ batch,      // EPI==2 only
    float* __restrict__ st_sum,         // EPI==1: sum[64]; EPI==2: pool[NG*64]
    float* __restrict__ st_sq,          // sumsq[64]
    float* __restrict__ cnt,            // EPI==2 only
    int* __restrict__ ctr,              // EPI==2 only: done-block counter
    const float* __restrict__ f_gamma,  // EPI==2 only: BN2 gamma
    const float* __restrict__ f_beta,   // EPI==2 only: BN2 beta
    float* __restrict__ f_out,          // EPI==2 only: final output
    int N) {
  __shared__ float s_in[NPB * INP];
  __shared__ __half s_Wa[D * MID];
  __shared__ __half s_Wb[MID * D];
  __shared__ float s_bna[FOLD_BN ? D : 1];
  __shared__ float s_bnb[FOLD_BN ? D : 1];
  __shared__ int s_cnt[2];

  int tid = threadIdx.x;

  // Stage Wa+Wb as fp16 (coalesced float4 reads, once per block).
  {
    const float4* wa4 = (const float4*)Wa;
    const float4* wb4 = (const float4*)Wb;
    __half2* sa2 = (__half2*)s_Wa;
    __half2* sb2 = (__half2*)s_Wb;
    constexpr int NW = D * MID / 4;
#pragma unroll
    for (int i = tid; i < NW; i += 512) {
      float4 a = wa4[i];
      float4 b = wb4[i];
      sa2[2 * i + 0] = __floats2half2_rn(a.x, a.y);
      sa2[2 * i + 1] = __floats2half2_rn(a.z, a.w);
      sb2[2 * i + 0] = __floats2half2_rn(b.x, b.y);
      sb2[2 * i + 1] = __floats2half2_rn(b.z, b.w);
    }
  }
  if (FOLD_BN && tid < D) {
    float mean = bn_sum[tid] * invN;
    float var = bn_sq[tid] * invN - mean * mean;
    float av = bn_gamma[tid] * rsqrtf(var + 1e-5f);
    s_bna[tid] = av;
    s_bnb[tid] = bn_beta[tid] - mean * av;
  }
  if (EPI == 2 && tid < 2) s_cnt[tid] = 0;
  __syncthreads();

  int base = blockIdx.x * NPB;

  // ---- Phase A: 8 lanes/node fp16 gather, uniform 8-wide rounds ----
  {
    int slot = tid >> 3;          // 0..63
    int q8 = tid & 7;             // lane covers features 8*q8 .. 8*q8+7
    int node = base + slot;
    if (node < N) {
      int d = min(deg[node], SLOT);
      const int* cl = col + node * SLOT;
      float acc[8];
      {
        HF4 s; s.f4 = feat4[(size_t)node * 8 + q8];   // self term
#pragma unroll
        for (int i = 0; i < 4; i++) {
          float2 f = __half22float2(s.h2[i]);
          acc[2 * i] = f.x; acc[2 * i + 1] = f.y;
        }
      }
      int dpad = (d + 7) & ~7;    // rounds of exactly 8 unconditional loads
      for (int j = 0; j < dpad; j += 8) {
        int4 sa = *(const int4*)(cl + j);     // SLOT=32: in-bounds
        int4 sb = *(const int4*)(cl + j + 4);
        int i0 = (j + 0 < d) ? sa.x : N;      // pad -> zero row
        int i1 = (j + 1 < d) ? sa.y : N;
        int i2 = (j + 2 < d) ? sa.z : N;
        int i3 = (j + 3 < d) ? sa.w : N;
        int i4 = (j + 4 < d) ? sb.x : N;
        int i5 = (j + 5 < d) ? sb.y : N;
        int i6 = (j + 6 < d) ? sb.z : N;
        int i7 = (j + 7 < d) ? sb.w : N;
        HF4 u0, u1, u2, u3, u4, u5, u6, u7;
        u0.f4 = feat4[(size_t)i0 * 8 + q8];
        u1.f4 = feat4[(size_t)i1 * 8 + q8];
        u2.f4 = feat4[(size_t)i2 * 8 + q8];
        u3.f4 = feat4[(size_t)i3 * 8 + q8];
        u4.f4 = feat4[(size_t)i4 * 8 + q8];
        u5.f4 = feat4[(size_t)i5 * 8 + q8];
        u6.f4 = feat4[(size_t)i6 * 8 + q8];
        u7.f4 = feat4[(size_t)i7 * 8 + q8];
#pragma unroll
        for (int i = 0; i < 4; i++) {
          float2 f0 = __half22float2(u0.h2[i]), f1 = __half22float2(u1.h2[i]);
          float2 f2 = __half22float2(u2.h2[i]), f3 = __half22float2(u3.h2[i]);
          float2 f4 = __half22float2(u4.h2[i]), f5 = __half22float2(u5.h2[i]);
          float2 f6 = __half22float2(u6.h2[i]), f7 = __half22float2(u7.h2[i]);
          acc[2 * i]     += (f0.x + f1.x + f2.x + f3.x) + (f4.x + f5.x + f6.x + f7.x);
          acc[2 * i + 1] += (f0.y + f1.y + f2.y + f3.y) + (f4.y + f5.y + f6.y + f7.y);
        }
      }
      if (FOLD_BN) {
        float dp = (float)(d + 1);
        int c = q8 * 8;
#pragma unroll
        for (int i = 0; i < 8; i++)
          acc[i] = s_bna[c + i] * acc[i] + dp * s_bnb[c + i];
      }
      *(float4*)&s_in[slot * INP + q8 * 8] =
          make_float4(acc[0], acc[1], acc[2], acc[3]);
      *(float4*)&s_in[slot * INP + q8 * 8 + 4] =
          make_float4(acc[4], acc[5], acc[6], acc[7]);
    }
  }
  __syncthreads();

  // ---- Phase B: register-tiled MLP (fp32 math, fp16 LDS weights) ----
  int q = tid & 15;               // lane within 16-group (output cols 4q..4q+3)
  int r2 = tid >> 4;              // 0..31 -> nodes 2r2, 2r2+1
  int n0 = 2 * r2, n1 = n0 + 1;
  int node0 = base + n0, node1 = base + n1;
  constexpr int C1 = MID / 16;    // stage-1 cols per thread (2 or 4)
  float4 o0, o1;
  {
    float acc0[C1], acc1[C1];
#pragma unroll
    for (int u = 0; u < C1; u++) { acc0[u] = ba[q * C1 + u]; acc1[u] = acc0[u]; }
#pragma unroll 4
    for (int j = 0; j < D; j++) {
      float v0 = s_in[n0 * INP + j];
      float v1 = s_in[n1 * INP + j];
      if constexpr (C1 == 2) {
        float2 w = __half22float2(((const __half2*)s_Wa)[j * 16 + q]);
        acc0[0] += v0 * w.x; acc0[1] += v0 * w.y;
        acc1[0] += v1 * w.x; acc1[1] += v1 * w.y;
      } else {
        HF2 u; u.f2 = ((const float2*)s_Wa)[j * 16 + q];
        float2 wA = __half22float2(u.h2[0]);
        float2 wB = __half22float2(u.h2[1]);
        acc0[0] += v0 * wA.x; acc0[1] += v0 * wA.y;
        acc0[2] += v0 * wB.x; acc0[3] += v0 * wB.y;
        acc1[0] += v1 * wA.x; acc1[1] += v1 * wA.y;
        acc1[2] += v1 * wB.x; acc1[3] += v1 * wB.y;
      }
    }
#pragma unroll
    for (int u = 0; u < C1; u++) {
      acc0[u] = fmaxf(acc0[u], 0.f);
      acc1[u] = fmaxf(acc1[u], 0.f);
    }

    // stage 2: cols 4q..4q+3; mid[k] owner lane = k/C1, reg = k%C1
    o0 = *(const float4*)(bb + q * 4);
    o1 = o0;
#pragma unroll 8
    for (int k = 0; k < MID; k++) {
      float m0 = __shfl(acc0[k % C1], k / C1, 16);
      float m1 = __shfl(acc1[k % C1], k / C1, 16);
      HF2 u; u.f2 = ((const float2*)s_Wb)[k * 16 + q];
      float2 wA = __half22float2(u.h2[0]);
      float2 wB = __half22float2(u.h2[1]);
      o0.x += m0 * wA.x; o0.y += m0 * wA.y; o0.z += m0 * wB.x; o0.w += m0 * wB.y;
      o1.x += m1 * wA.x; o1.y += m1 * wA.y; o1.z += m1 * wB.x; o1.w += m1 * wB.y;
    }
    o0.x = fmaxf(o0.x, 0.f); o0.y = fmaxf(o0.y, 0.f);
    o0.z = fmaxf(o0.z, 0.f); o0.w = fmaxf(o0.w, 0.f);
    o1.x = fmaxf(o1.x, 0.f); o1.y = fmaxf(o1.y, 0.f);
    o1.z = fmaxf(o1.z, 0.f); o1.w = fmaxf(o1.w, 0.f);
    if (EPI == 1) {
      if (node0 < N) {
        HF2 u;
        u.h2[0] = __floats2half2_rn(o0.x, o0.y);
        u.h2[1] = __floats2half2_rn(o0.z, o0.w);
        out2[(size_t)node0 * 16 + q] = u.f2;
      }
      if (node1 < N) {
        HF2 u;
        u.h2[0] = __floats2half2_rn(o1.x, o1.y);
        u.h2[1] = __floats2half2_rn(o1.z, o1.w);
        out2[(size_t)node1 * 16 + q] = u.f2;
      }
    }
    if (node0 >= N) o0 = make_float4(0.f, 0.f, 0.f, 0.f);
    if (node1 >= N) o1 = make_float4(0.f, 0.f, 0.f, 0.f);
  }

  if (EPI == 1) {
    // ---- BN-stats epilogue: block tree-reduce sum + sumsq, 128 atomics ----
    __syncthreads();   // all s_in reads done; reuse s_in as reduce buffer
    *(float4*)&s_in[r2 * INP + q * 4] =
        make_float4(o0.x + o1.x, o0.y + o1.y, o0.z + o1.z, o0.w + o1.w);
    *(float4*)&s_in[(32 + r2) * INP + q * 4] =
        make_float4(o0.x * o0.x + o1.x * o1.x, o0.y * o0.y + o1.y * o1.y,
                    o0.z * o0.z + o1.z * o1.z, o0.w * o0.w + o1.w * o1.w);
    __syncthreads();
    tree_reduce_2x32(s_in, tid);
    if (tid < D) {
      atomicAdd(&st_sum[tid], s_in[tid]);
      atomicAdd(&st_sq[tid], s_in[32 * INP + tid]);
    }
  }

  if (EPI == 2) {
    // ---- Pool epilogue: <=2 graphs per 64-node block (sorted batch) ----
    int b0 = (node0 < N) ? batch[node0] : -1;
    int b1 = (node1 < N) ? batch[node1] : -1;
    int g_lo = batch[base];
    int g_hi = batch[min(base + NPB - 1, N - 1)];

    __syncthreads();   // s_in reads done; s_cnt init visible
    // ONLY q==0: the 16 q-lanes of an r2-group share the same two nodes.
    if (q == 0) {
      atomicAdd(&s_cnt[0], (b0 == g_lo ? 1 : 0) + (b1 == g_lo ? 1 : 0));
      if (g_hi != g_lo)
        atomicAdd(&s_cnt[1], (b0 == g_hi ? 1 : 0) + (b1 == g_hi ? 1 : 0));
    }

    float w0 = (b0 == g_lo) ? 1.f : 0.f;
    float w1 = (b1 == g_lo) ? 1.f : 0.f;
    *(float4*)&s_in[r2 * INP + q * 4] =
        make_float4(w0 * o0.x + w1 * o1.x, w0 * o0.y + w1 * o1.y,
                    w0 * o0.z + w1 * o1.z, w0 * o0.w + w1 * o1.w);
    *(float4*)&s_in[(32 + r2) * INP + q * 4] =
        make_float4(o0.x * o0.x + o1.x * o1.x, o0.y * o0.y + o1.y * o1.y,
                    o0.z * o0.z + o1.z * o1.z, o0.w * o0.w + o1.w * o1.w);
    __syncthreads();
    tree_reduce_2x32(s_in, tid);
    if (tid < D) {
      atomicAdd(&st_sum[g_lo * D + tid], s_in[tid]);
      atomicAdd(&st_sq[tid], s_in[32 * INP + tid]);
    }
    if (tid == 0) atomicAdd(&cnt[g_lo], (float)s_cnt[0]);

    if (g_hi != g_lo) {   // block-uniform branch
      __syncthreads();
      float u0 = (b0 == g_hi) ? 1.f : 0.f;
      float u1 = (b1 == g_hi) ? 1.f : 0.f;
      *(float4*)&s_in[r2 * INP + q * 4] =
          make_float4(u0 * o0.x + u1 * o1.x, u0 * o0.y + u1 * o1.y,
                      u0 * o0.z + u1 * o1.z, u0 * o0.w + u1 * o1.w);
      *(float4*)&s_in[(32 + r2) * INP + q * 4] = make_float4(0.f, 0.f, 0.f, 0.f);
      __syncthreads();
      tree_reduce_2x32(s_in, tid);
      if (tid < D) atomicAdd(&st_sum[g_hi * D + tid], s_in[tid]);
      if (tid == 0) atomicAdd(&cnt[g_hi], (float)s_cnt[1]);
    }

    // ---- Folded final: last finished block computes BN2 + mean output ----
    __threadfence();              // order this block's atomics before ctr
    __syncthreads();
    if (tid == 0) s_cnt[0] = atomicAdd(ctr, 1);
    __syncthreads();
    if (s_cnt[0] == (int)gridDim.x - 1 && tid < D) {
      // All pool/cnt/sq writers finished (ctr ordering); values live in L2
      // (written by atomics). Read with device-scope atomic loads to bypass
      // potentially-stale L1.
      float pv[NG];
      float s = 0.f;
#pragma unroll
      for (int g = 0; g < NG; g++) {
        pv[g] = __hip_atomic_load(&st_sum[g * D + tid], __ATOMIC_RELAXED,
                                  __HIP_MEMORY_SCOPE_AGENT);
        s += pv[g];
      }
      float sqv = __hip_atomic_load(&st_sq[tid], __ATOMIC_RELAXED,
                                    __HIP_MEMORY_SCOPE_AGENT);
      float mean = s * invN;
      float var = sqv * invN - mean * mean;
      float a = f_gamma[tid] * rsqrtf(var + 1e-5f);
      float b = f_beta[tid] - mean * a;
#pragma unroll
      for (int g = 0; g < NG; g++) {
        float n = __hip_atomic_load(&cnt[g], __ATOMIC_RELAXED,
                                    __HIP_MEMORY_SCOPE_AGENT);
        f_out[g * D + tid] = (a * pv[g] + n * b) / fmaxf(n, 1.f);
      }
    }
  }
}

extern "C" void kernel_launch(void* const* d_in, const int* in_sizes, int n_in,
                              void* d_out, int out_size, void* d_ws, size_t ws_size,
                              hipStream_t stream) {
  const float* x   = (const float*)d_in[0];
  const int* ei    = (const int*)d_in[1];
  const int* batch = (const int*)d_in[2];
  const float* W1a = (const float*)d_in[5];
  const float* b1a = (const float*)d_in[6];
  const float* W1b = (const float*)d_in[7];
  const float* b1b = (const float*)d_in[8];
  const float* g1  = (const float*)d_in[9];
  const float* be1 = (const float*)d_in[10];
  const float* W2a = (const float*)d_in[11];
  const float* b2a = (const float*)d_in[12];
  const float* W2b = (const float*)d_in[13];
  const float* b2b = (const float*)d_in[14];
  const float* g2  = (const float*)d_in[15];
  const float* be2 = (const float*)d_in[16];

  int N = in_sizes[0] / D;        // 100000
  int E = in_sizes[1] / 2;        // 1600000
  int per = E / NG;               // 100000
  int tmul = N / NG;              // 6250
  float invN = 1.f / (float)N;

  float* ws = (float*)d_ws;
  size_t ndh = (size_t)(N + 1) * D / 2;  // fp16 table size in floats (N+1 rows)
  float* h1h = ws;                       // h1 (pre-BN) fp16 table, N+1 rows
  float* xh  = ws + ndh;                 // x fp16 table, N+1 rows
  int*   col = (int*)(ws + 2 * ndh);     // CSR src lists (N*SLOT ints)
  float* stats = ws + 2 * ndh + (size_t)N * SLOT;
  float* sum1 = stats;                   // 64
  float* sq1  = stats + 64;              // 64
  float* pool = stats + 128;             // 16*64
  float* cnt  = stats + 128 + NG * D;    // 16
  float* sq2  = stats + 144 + NG * D;    // 64
  int*   ctr  = (int*)(stats + 208 + NG * D);  // 1 (+pad to 16)
  int*   fill = (int*)(stats + 224 + NG * D);  // N ints (degree counts)

  // Zero stats + ctr + fill (contiguous, ~0.4 MB) in one shot.
  hipMemsetAsync(stats, 0, (224 + NG * D + N) * sizeof(float), stream);

  // Fused prep: x->fp16 + pad-row zero + CSR build (n4 == E here).
  int n4 = N * D / 4;
  int pgrid = (max(n4, E) + 255) / 256;
  prep_kernel<<<pgrid, 256, 0, stream>>>(
      x, (float2*)xh, n4,
      (float4*)(xh + (size_t)N * D / 2),
      (float4*)(h1h + (size_t)N * D / 2),
      ei, fill, col, E, per, tmul);

  int fblocks = (N + NPB - 1) / NPB;   // 1563

  // Layer 1: gather(xh) + MLP1 -> h1h (fp16, pre-BN) + BN1-stats epilogue
  fused_layer_kernel<32, false, 1><<<fblocks, 512, 0, stream>>>(
      (const float4*)xh, col, fill, nullptr, nullptr, nullptr, nullptr, invN,
      W1a, b1a, W1b, b1b, (float2*)h1h, nullptr, sum1, sq1, nullptr,
      nullptr, nullptr, nullptr, nullptr, N);

  // Layer 2: BN1 folded into gather input; pool + sumsq epilogue (no h2);
  // last block computes the final output (folded final_kernel).
  fused_layer_kernel<64, true, 2><<<fblocks, 512, 0, stream>>>(
      (const float4*)h1h, col, fill, sum1, sq1, g1, be1, invN,
      W2a, b2a, W2b, b2b, nullptr, batch, pool, sq2, cnt,
      ctr, g2, be2, (float*)d_out, N);
}

// Round 17
// 259.427 us; speedup vs baseline: 1.6729x; 1.6276x over previous
//
#include <hip/hip_runtime.h>
#include <hip/hip_fp16.h>

#define NG 16     // num_graphs (fixed by problem)
#define D 64      // feature width at every aggregation point
#define SLOT 32   // CSR slots/node; max in-degree ~Poisson(8.5), P(>=32)~1e-11
#define INP 68    // padded LDS row stride (D+4): float4-aligned, conflict-free
#define NPB 64    // nodes per block (512 threads, 8 lanes/node)

// fp16 feature rows: 64 halfs = 128 B = 8 float4s. Tables have N+1 rows;
// row N is all-zero (gather pad target).
union HF4 { float4 f4; __half2 h2[4]; };
union HF2 { float2 f2; __half2 h2[2]; };

// ---------------------------------------------------------------------------
// Fused prep (R14's win): x->fp16 convert (t < n4) + CSR build (t < E) +
// pad-row zeroing. n4 == E == 1.6M here, one grid covers both jobs.
// fill[] must be zeroed beforehand (memset on same stream).
// ---------------------------------------------------------------------------
__global__ void prep_kernel(const float* __restrict__ x,
                            float2* __restrict__ xh, int n4,
                            float4* __restrict__ xz, float4* __restrict__ hz,
                            const int* __restrict__ ei,
                            int* __restrict__ fill, int* __restrict__ col,
                            int E, int per, int tmul) {
  int t = blockIdx.x * 256 + threadIdx.x;
  if (blockIdx.x == 0 && threadIdx.x < 16) {
    float4 z = make_float4(0.f, 0.f, 0.f, 0.f);
    if (threadIdx.x < 8) xz[threadIdx.x] = z;
    else hz[threadIdx.x - 8] = z;
  }
  if (t < n4) {
    float4 v = ((const float4*)x)[t];
    HF2 u;
    u.h2[0] = __floats2half2_rn(v.x, v.y);
    u.h2[1] = __floats2half2_rn(v.z, v.w);
    xh[t] = u.f2;
  }
  if (t < E) {
    int src = ei[t];
    int dst = ei[E + t];
    int thr = (t / per) * tmul;       // compiler magic-div
    if (src >= thr && dst >= thr) {
      int k = atomicAdd(&fill[dst], 1);
      if (k < SLOT) col[dst * SLOT + k] = src;
    }
  }
}

// Tree-reduce rows 0..31 (+32..63 as a second half) of s_in down to row 0 /
// row 32. 64 float columns per half, float4 per lane.
__device__ __forceinline__ void tree_reduce_2x32(float* s_in, int tid) {
#pragma unroll
  for (int s = 16; s >= 1; s >>= 1) {
    if (tid < 32 * s) {
      int h = tid / (16 * s);          // 0 = first half, 1 = second half
      int r = (tid / 16) % s;
      int qq = tid & 15;
      float4* a = (float4*)&s_in[(h * 32 + r) * INP + qq * 4];
      const float4 b = *(const float4*)&s_in[(h * 32 + r + s) * INP + qq * 4];
      a->x += b.x; a->y += b.y; a->z += b.z; a->w += b.w;
    }
    __syncthreads();
  }
}

// ---------------------------------------------------------------------------
// Fused layer (R13's measured-best, 69us/layer): fp16 gather + (optional BN
// fold) + fp32 MLP + epilogue.
//  EPI==1 (layer 1): store h as fp16 to `out2`, block-reduce BN stats.
//  EPI==2 (layer 2): no per-node store; per-graph pool sums + sumsq + counts.
// NO device-scope fences anywhere (R16 lesson: __threadfence per block
// invalidates the XCD L2 on gfx950 -> gather locality destroyed, 3.6x slow).
// Block = 512 threads, 64 nodes (R12: 256-thr blocks regressed).
//  Phase A: 8 lanes/node, rounds of EXACTLY 8 unconditional float4 loads
//    (pad -> zero row N): avg-degree nodes finish gather in ONE latency trip.
//  Phase B: thread (q,r2) -> nodes {2r2,2r2+1}; stage-1 mids in registers,
//    stage-2 via 16-lane __shfl; Wa+Wb in LDS as fp16.
// __launch_bounds__ 2nd arg (empirical, 512-thr blocks): VGPR cap = 256/arg.
//   arg=8 -> 32 (R5 spill), arg=4 -> 64 (R6 spill), arg=2 -> 128 (safe).
// ---------------------------------------------------------------------------
template <int MID, bool FOLD_BN, int EPI>
__global__ __launch_bounds__(512, 2) void fused_layer_kernel(
    const float4* __restrict__ feat4,   // fp16 table, 8 float4/row, N+1 rows
    const int* __restrict__ col, const int* __restrict__ deg,
    const float* __restrict__ bn_sum, const float* __restrict__ bn_sq,
    const float* __restrict__ bn_gamma, const float* __restrict__ bn_beta,
    float invN,
    const float* __restrict__ Wa, const float* __restrict__ ba,
    const float* __restrict__ Wb, const float* __restrict__ bb,
    float2* __restrict__ out2,          // EPI==1 only (fp16 rows)
    const int* __restrict__ batch,      // EPI==2 only
    float* __restrict__ st_sum,         // EPI==1: sum[64]; EPI==2: pool[NG*64]
    float* __restrict__ st_sq,          // sumsq[64]
    float* __restrict__ cnt,            // EPI==2 only
    int N) {
  __shared__ float s_in[NPB * INP];
  __shared__ __half s_Wa[D * MID];
  __shared__ __half s_Wb[MID * D];
  __shared__ float s_bna[FOLD_BN ? D : 1];
  __shared__ float s_bnb[FOLD_BN ? D : 1];
  __shared__ int s_cnt[2];

  int tid = threadIdx.x;

  // Stage Wa+Wb as fp16 (coalesced float4 reads, once per block).
  {
    const float4* wa4 = (const float4*)Wa;
    const float4* wb4 = (const float4*)Wb;
    __half2* sa2 = (__half2*)s_Wa;
    __half2* sb2 = (__half2*)s_Wb;
    constexpr int NW = D * MID / 4;
#pragma unroll
    for (int i = tid; i < NW; i += 512) {
      float4 a = wa4[i];
      float4 b = wb4[i];
      sa2[2 * i + 0] = __floats2half2_rn(a.x, a.y);
      sa2[2 * i + 1] = __floats2half2_rn(a.z, a.w);
      sb2[2 * i + 0] = __floats2half2_rn(b.x, b.y);
      sb2[2 * i + 1] = __floats2half2_rn(b.z, b.w);
    }
  }
  if (FOLD_BN && tid < D) {
    float mean = bn_sum[tid] * invN;
    float var = bn_sq[tid] * invN - mean * mean;
    float av = bn_gamma[tid] * rsqrtf(var + 1e-5f);
    s_bna[tid] = av;
    s_bnb[tid] = bn_beta[tid] - mean * av;
  }
  if (EPI == 2 && tid < 2) s_cnt[tid] = 0;
  __syncthreads();

  int base = blockIdx.x * NPB;

  // ---- Phase A: 8 lanes/node fp16 gather, uniform 8-wide rounds ----
  {
    int slot = tid >> 3;          // 0..63
    int q8 = tid & 7;             // lane covers features 8*q8 .. 8*q8+7
    int node = base + slot;
    if (node < N) {
      int d = min(deg[node], SLOT);
      const int* cl = col + node * SLOT;
      float acc[8];
      {
        HF4 s; s.f4 = feat4[(size_t)node * 8 + q8];   // self term
#pragma unroll
        for (int i = 0; i < 4; i++) {
          float2 f = __half22float2(s.h2[i]);
          acc[2 * i] = f.x; acc[2 * i + 1] = f.y;
        }
      }
      int dpad = (d + 7) & ~7;    // rounds of exactly 8 unconditional loads
      for (int j = 0; j < dpad; j += 8) {
        int4 sa = *(const int4*)(cl + j);     // SLOT=32: in-bounds
        int4 sb = *(const int4*)(cl + j + 4);
        int i0 = (j + 0 < d) ? sa.x : N;      // pad -> zero row
        int i1 = (j + 1 < d) ? sa.y : N;
        int i2 = (j + 2 < d) ? sa.z : N;
        int i3 = (j + 3 < d) ? sa.w : N;
        int i4 = (j + 4 < d) ? sb.x : N;
        int i5 = (j + 5 < d) ? sb.y : N;
        int i6 = (j + 6 < d) ? sb.z : N;
        int i7 = (j + 7 < d) ? sb.w : N;
        HF4 u0, u1, u2, u3, u4, u5, u6, u7;
        u0.f4 = feat4[(size_t)i0 * 8 + q8];
        u1.f4 = feat4[(size_t)i1 * 8 + q8];
        u2.f4 = feat4[(size_t)i2 * 8 + q8];
        u3.f4 = feat4[(size_t)i3 * 8 + q8];
        u4.f4 = feat4[(size_t)i4 * 8 + q8];
        u5.f4 = feat4[(size_t)i5 * 8 + q8];
        u6.f4 = feat4[(size_t)i6 * 8 + q8];
        u7.f4 = feat4[(size_t)i7 * 8 + q8];
#pragma unroll
        for (int i = 0; i < 4; i++) {
          float2 f0 = __half22float2(u0.h2[i]), f1 = __half22float2(u1.h2[i]);
          float2 f2 = __half22float2(u2.h2[i]), f3 = __half22float2(u3.h2[i]);
          float2 f4 = __half22float2(u4.h2[i]), f5 = __half22float2(u5.h2[i]);
          float2 f6 = __half22float2(u6.h2[i]), f7 = __half22float2(u7.h2[i]);
          acc[2 * i]     += (f0.x + f1.x + f2.x + f3.x) + (f4.x + f5.x + f6.x + f7.x);
          acc[2 * i + 1] += (f0.y + f1.y + f2.y + f3.y) + (f4.y + f5.y + f6.y + f7.y);
        }
      }
      if (FOLD_BN) {
        float dp = (float)(d + 1);
        int c = q8 * 8;
#pragma unroll
        for (int i = 0; i < 8; i++)
          acc[i] = s_bna[c + i] * acc[i] + dp * s_bnb[c + i];
      }
      *(float4*)&s_in[slot * INP + q8 * 8] =
          make_float4(acc[0], acc[1], acc[2], acc[3]);
      *(float4*)&s_in[slot * INP + q8 * 8 + 4] =
          make_float4(acc[4], acc[5], acc[6], acc[7]);
    }
  }
  __syncthreads();

  // ---- Phase B: register-tiled MLP (fp32 math, fp16 LDS weights) ----
  int q = tid & 15;               // lane within 16-group (output cols 4q..4q+3)
  int r2 = tid >> 4;              // 0..31 -> nodes 2r2, 2r2+1
  int n0 = 2 * r2, n1 = n0 + 1;
  int node0 = base + n0, node1 = base + n1;
  constexpr int C1 = MID / 16;    // stage-1 cols per thread (2 or 4)
  float4 o0, o1;
  {
    float acc0[C1], acc1[C1];
#pragma unroll
    for (int u = 0; u < C1; u++) { acc0[u] = ba[q * C1 + u]; acc1[u] = acc0[u]; }
#pragma unroll 4
    for (int j = 0; j < D; j++) {
      float v0 = s_in[n0 * INP + j];
      float v1 = s_in[n1 * INP + j];
      if constexpr (C1 == 2) {
        float2 w = __half22float2(((const __half2*)s_Wa)[j * 16 + q]);
        acc0[0] += v0 * w.x; acc0[1] += v0 * w.y;
        acc1[0] += v1 * w.x; acc1[1] += v1 * w.y;
      } else {
        HF2 u; u.f2 = ((const float2*)s_Wa)[j * 16 + q];
        float2 wA = __half22float2(u.h2[0]);
        float2 wB = __half22float2(u.h2[1]);
        acc0[0] += v0 * wA.x; acc0[1] += v0 * wA.y;
        acc0[2] += v0 * wB.x; acc0[3] += v0 * wB.y;
        acc1[0] += v1 * wA.x; acc1[1] += v1 * wA.y;
        acc1[2] += v1 * wB.x; acc1[3] += v1 * wB.y;
      }
    }
#pragma unroll
    for (int u = 0; u < C1; u++) {
      acc0[u] = fmaxf(acc0[u], 0.f);
      acc1[u] = fmaxf(acc1[u], 0.f);
    }

    // stage 2: cols 4q..4q+3; mid[k] owner lane = k/C1, reg = k%C1
    o0 = *(const float4*)(bb + q * 4);
    o1 = o0;
#pragma unroll 8
    for (int k = 0; k < MID; k++) {
      float m0 = __shfl(acc0[k % C1], k / C1, 16);
      float m1 = __shfl(acc1[k % C1], k / C1, 16);
      HF2 u; u.f2 = ((const float2*)s_Wb)[k * 16 + q];
      float2 wA = __half22float2(u.h2[0]);
      float2 wB = __half22float2(u.h2[1]);
      o0.x += m0 * wA.x; o0.y += m0 * wA.y; o0.z += m0 * wB.x; o0.w += m0 * wB.y;
      o1.x += m1 * wA.x; o1.y += m1 * wA.y; o1.z += m1 * wB.x; o1.w += m1 * wB.y;
    }
    o0.x = fmaxf(o0.x, 0.f); o0.y = fmaxf(o0.y, 0.f);
    o0.z = fmaxf(o0.z, 0.f); o0.w = fmaxf(o0.w, 0.f);
    o1.x = fmaxf(o1.x, 0.f); o1.y = fmaxf(o1.y, 0.f);
    o1.w = fmaxf(o1.w, 0.f); o1.z = fmaxf(o1.z, 0.f);
    if (EPI == 1) {
      if (node0 < N) {
        HF2 u;
        u.h2[0] = __floats2half2_rn(o0.x, o0.y);
        u.h2[1] = __floats2half2_rn(o0.z, o0.w);
        out2[(size_t)node0 * 16 + q] = u.f2;
      }
      if (node1 < N) {
        HF2 u;
        u.h2[0] = __floats2half2_rn(o1.x, o1.y);
        u.h2[1] = __floats2half2_rn(o1.z, o1.w);
        out2[(size_t)node1 * 16 + q] = u.f2;
      }
    }
    if (node0 >= N) o0 = make_float4(0.f, 0.f, 0.f, 0.f);
    if (node1 >= N) o1 = make_float4(0.f, 0.f, 0.f, 0.f);
  }

  if (EPI == 1) {
    // ---- BN-stats epilogue: block tree-reduce sum + sumsq, 128 atomics ----
    __syncthreads();   // all s_in reads done; reuse s_in as reduce buffer
    *(float4*)&s_in[r2 * INP + q * 4] =
        make_float4(o0.x + o1.x, o0.y + o1.y, o0.z + o1.z, o0.w + o1.w);
    *(float4*)&s_in[(32 + r2) * INP + q * 4] =
        make_float4(o0.x * o0.x + o1.x * o1.x, o0.y * o0.y + o1.y * o1.y,
                    o0.z * o0.z + o1.z * o1.z, o0.w * o0.w + o1.w * o1.w);
    __syncthreads();
    tree_reduce_2x32(s_in, tid);
    if (tid < D) {
      atomicAdd(&st_sum[tid], s_in[tid]);
      atomicAdd(&st_sq[tid], s_in[32 * INP + tid]);
    }
  }

  if (EPI == 2) {
    // ---- Pool epilogue: <=2 graphs per 64-node block (sorted batch) ----
    int b0 = (node0 < N) ? batch[node0] : -1;
    int b1 = (node1 < N) ? batch[node1] : -1;
    int g_lo = batch[base];
    int g_hi = batch[min(base + NPB - 1, N - 1)];

    __syncthreads();   // s_in reads done; s_cnt init visible
    // ONLY q==0: the 16 q-lanes of an r2-group share the same two nodes.
    if (q == 0) {
      atomicAdd(&s_cnt[0], (b0 == g_lo ? 1 : 0) + (b1 == g_lo ? 1 : 0));
      if (g_hi != g_lo)
        atomicAdd(&s_cnt[1], (b0 == g_hi ? 1 : 0) + (b1 == g_hi ? 1 : 0));
    }

    float w0 = (b0 == g_lo) ? 1.f : 0.f;
    float w1 = (b1 == g_lo) ? 1.f : 0.f;
    *(float4*)&s_in[r2 * INP + q * 4] =
        make_float4(w0 * o0.x + w1 * o1.x, w0 * o0.y + w1 * o1.y,
                    w0 * o0.z + w1 * o1.z, w0 * o0.w + w1 * o1.w);
    *(float4*)&s_in[(32 + r2) * INP + q * 4] =
        make_float4(o0.x * o0.x + o1.x * o1.x, o0.y * o0.y + o1.y * o1.y,
                    o0.z * o0.z + o1.z * o1.z, o0.w * o0.w + o1.w * o1.w);
    __syncthreads();
    tree_reduce_2x32(s_in, tid);
    if (tid < D) {
      atomicAdd(&st_sum[g_lo * D + tid], s_in[tid]);
      atomicAdd(&st_sq[tid], s_in[32 * INP + tid]);
    }
    if (tid == 0) atomicAdd(&cnt[g_lo], (float)s_cnt[0]);

    if (g_hi != g_lo) {   // block-uniform branch
      __syncthreads();
      float u0 = (b0 == g_hi) ? 1.f : 0.f;
      float u1 = (b1 == g_hi) ? 1.f : 0.f;
      *(float4*)&s_in[r2 * INP + q * 4] =
          make_float4(u0 * o0.x + u1 * o1.x, u0 * o0.y + u1 * o1.y,
                      u0 * o0.z + u1 * o1.z, u0 * o0.w + u1 * o1.w);
      *(float4*)&s_in[(32 + r2) * INP + q * 4] = make_float4(0.f, 0.f, 0.f, 0.f);
      __syncthreads();
      tree_reduce_2x32(s_in, tid);
      if (tid < D) atomicAdd(&st_sum[g_hi * D + tid], s_in[tid]);
      if (tid == 0) atomicAdd(&cnt[g_hi], (float)s_cnt[1]);
    }
  }
}

// ---------------------------------------------------------------------------
// Final: BN2 coeffs from (Σ_g pool, sq) + fused affine + mean divide.
// ---------------------------------------------------------------------------
__global__ void final_kernel(const float* __restrict__ pool,
                             const float* __restrict__ cnt,
                             const float* __restrict__ sq,
                             const float* __restrict__ gamma,
                             const float* __restrict__ beta,
                             float invN, float* __restrict__ out) {
  int c = threadIdx.x;   // 64 threads
  float s = 0.f;
#pragma unroll
  for (int g = 0; g < NG; g++) s += pool[g * D + c];
  float mean = s * invN;
  float var = sq[c] * invN - mean * mean;
  float a = gamma[c] * rsqrtf(var + 1e-5f);
  float b = beta[c] - mean * a;
#pragma unroll
  for (int g = 0; g < NG; g++) {
    float n = cnt[g];
    out[g * D + c] = (a * pool[g * D + c] + n * b) / fmaxf(n, 1.f);
  }
}

extern "C" void kernel_launch(void* const* d_in, const int* in_sizes, int n_in,
                              void* d_out, int out_size, void* d_ws, size_t ws_size,
                              hipStream_t stream) {
  const float* x   = (const float*)d_in[0];
  const int* ei    = (const int*)d_in[1];
  const int* batch = (const int*)d_in[2];
  const float* W1a = (const float*)d_in[5];
  const float* b1a = (const float*)d_in[6];
  const float* W1b = (const float*)d_in[7];
  const float* b1b = (const float*)d_in[8];
  const float* g1  = (const float*)d_in[9];
  const float* be1 = (const float*)d_in[10];
  const float* W2a = (const float*)d_in[11];
  const float* b2a = (const float*)d_in[12];
  const float* W2b = (const float*)d_in[13];
  const float* b2b = (const float*)d_in[14];
  const float* g2  = (const float*)d_in[15];
  const float* be2 = (const float*)d_in[16];

  int N = in_sizes[0] / D;        // 100000
  int E = in_sizes[1] / 2;        // 1600000
  int per = E / NG;               // 100000
  int tmul = N / NG;              // 6250
  float invN = 1.f / (float)N;

  float* ws = (float*)d_ws;
  size_t ndh = (size_t)(N + 1) * D / 2;  // fp16 table size in floats (N+1 rows)
  float* h1h = ws;                       // h1 (pre-BN) fp16 table, N+1 rows
  float* xh  = ws + ndh;                 // x fp16 table, N+1 rows
  int*   col = (int*)(ws + 2 * ndh);     // CSR src lists (N*SLOT ints)
  float* stats = ws + 2 * ndh + (size_t)N * SLOT;
  float* sum1 = stats;                   // 64
  float* sq1  = stats + 64;              // 64
  float* pool = stats + 128;             // 16*64
  float* cnt  = stats + 128 + NG * D;    // 16
  float* sq2  = stats + 144 + NG * D;    // 64
  int*   fill = (int*)(stats + 208 + NG * D);  // N ints (degree counts)

  // Zero stats + fill (contiguous, ~0.4 MB) in one shot.
  hipMemsetAsync(stats, 0, (208 + NG * D + N) * sizeof(float), stream);

  // Fused prep: x->fp16 + pad-row zero + CSR build (n4 == E here).
  int n4 = N * D / 4;
  int pgrid = (max(n4, E) + 255) / 256;
  prep_kernel<<<pgrid, 256, 0, stream>>>(
      x, (float2*)xh, n4,
      (float4*)(xh + (size_t)N * D / 2),
      (float4*)(h1h + (size_t)N * D / 2),
      ei, fill, col, E, per, tmul);

  int fblocks = (N + NPB - 1) / NPB;   // 1563

  // Layer 1: gather(xh) + MLP1 -> h1h (fp16, pre-BN) + BN1-stats epilogue
  fused_layer_kernel<32, false, 1><<<fblocks, 512, 0, stream>>>(
      (const float4*)xh, col, fill, nullptr, nullptr, nullptr, nullptr, invN,
      W1a, b1a, W1b, b1b, (float2*)h1h, nullptr, sum1, sq1, nullptr, N);

  // Layer 2: BN1 folded into gather input; pool + sumsq epilogue (no h2)
  fused_layer_kernel<64, true, 2><<<fblocks, 512, 0, stream>>>(
      (const float4*)h1h, col, fill, sum1, sq1, g1, be1, invN,
      W2a, b2a, W2b, b2b, nullptr, batch, pool, sq2, cnt, N);

  // BN2 coeffs + affine + mean.
  final_kernel<<<1, 64, 0, stream>>>(pool, cnt, sq2, g2, be2, invN, (float*)d_out);
}